// Round 17
// baseline (83.053 us; speedup 1.0000x reference)
//
#include <hip/hip_runtime.h>
#include <stdint.h>

typedef unsigned long long u64;
typedef unsigned int u32;
typedef float f2 __attribute__((ext_vector_type(2)));
typedef float f4 __attribute__((ext_vector_type(4)));

// ---- cross-lane helpers ----
__device__ __forceinline__ float dpp_shr1_f(float v, int fill_bits) {
  // within each 16-lane row: lane i <- lane i-1; row-lead takes fill
  return __int_as_float(__builtin_amdgcn_update_dpp(
      fill_bits, __float_as_int(v), 0x111 /*row_shr:1*/, 0xF, 0xF, false));
}
__device__ __forceinline__ int dpp_shr1_i(int v) {
  return __builtin_amdgcn_update_dpp(0, v, 0x111, 0xF, 0xF, false);
}
__device__ __forceinline__ float rdlane_f(float v, int lane) {
  return __int_as_float(__builtin_amdgcn_readlane(__float_as_int(v), lane));
}
// order-preserving float-bits -> u32 (monotone over all floats incl. negatives)
__device__ __forceinline__ u32 fkey(u32 s) {
  return s ^ ((u32)((int)s >> 31) | 0x80000000u);
}

// pair records for 128-pt chunks: pair (n0 = k*128+t, n1 = n0+64), t=0..63
// rec0 = {-2x0,-2x1,-2y0,-2y1}, rec1 = {-2z0,-2z1, pn0, pn1}
// x(-2) is exact so q*(-2p) == -2*inner bit-exactly; pn in numpy order.
__global__ void prep_pack2(const float* __restrict__ pc, float4* __restrict__ pp,
                           int B, int N) {
  int r = blockIdx.x * blockDim.x + threadIdx.x;  // pair id
  int H = N >> 1;
  if (r >= B * H) return;
  int b = r / H;
  int j = r - b * H;
  int k = j >> 6, t = j & 63;
  int n0 = (k << 7) + t, n1 = n0 + 64;
  const float* p = pc + (size_t)b * 3 * N;
  float x0 = p[n0], x1 = p[n1];
  float y0 = p[N + n0], y1 = p[N + n1];
  float z0 = p[2 * N + n0], z1 = p[2 * N + n1];
  float pn0 = __fadd_rn(__fadd_rn(__fmul_rn(x0, x0), __fmul_rn(y0, y0)),
                        __fmul_rn(z0, z0));
  float pn1 = __fadd_rn(__fadd_rn(__fmul_rn(x1, x1), __fmul_rn(y1, y1)),
                        __fmul_rn(z1, z1));
  pp[2 * r] = make_float4(__fmul_rn(x0, -2.0f), __fmul_rn(x1, -2.0f),
                          __fmul_rn(y0, -2.0f), __fmul_rn(y1, -2.0f));
  pp[2 * r + 1] = make_float4(__fmul_rn(z0, -2.0f), __fmul_rn(z1, -2.0f),
                              pn0, pn1);
}

template <bool PACKED>
__global__ __launch_bounds__(256, 8) void knn17(
    const float* __restrict__ pc,    // (B,3,N)
    const float* __restrict__ qc,    // (B,3,M)
    const float* __restrict__ temp,  // scalar
    const float4* __restrict__ pp,   // packed pair records
    float* __restrict__ out,         // (B,3,M)
    int B, int N, int M) {
#pragma clang fp contract(off)
  const float INF = __int_as_float(0x7f800000);
  const int NINF_BITS = (int)0xff800000;

  // double-buffered super-chunks: 2 x 512 pts x 16 B = 16 KiB
  __shared__ __attribute__((aligned(16))) char smem[16384];

  int tid = threadIdx.x;
  int lane = tid & 63;
  int widx = tid >> 6;  // wave 0..3; also this wave's staging chunk
  // wave-uniform query id -> scalar bases; 4 waves of a block share batch b
  int qid = __builtin_amdgcn_readfirstlane(blockIdx.x * 4 + widx);
  int b = qid >> 11;                      // M = 2048; 512 blocks per batch
  int q = qid & 2047;

  float qx = qc[(b * 3 + 0) * M + q];
  float qy = qc[(b * 3 + 1) * M + q];
  float qz = qc[(b * 3 + 2) * M + q];
  float qn = __fadd_rn(__fadd_rn(__fmul_rn(qx, qx), __fmul_rn(qy, qy)),
                       __fmul_rn(qz, qz));
  f2 qx2 = {qx, qx}, qy2 = {qy, qy}, qz2 = {qz, qz}, qn2 = {qn, qn};

  // distributed top-16: lane (l&15) holds entry (l&15), ascending; all four
  // 16-lane rows mirror the same list (updates are wave-uniform).
  float val = INF;
  int idx = 0;
  float thresh = INF;

  const float* __restrict__ pcb = pc + (size_t)b * 3 * N;

  // re-ballot insert loop WITH LANE-KILL (R16 bug fix): after inserting
  // candidate s, kill lane s so it cannot re-qualify. Processing order is
  // then provably ascending-index with the exact evolving threshold ==
  // sequential scan == jax top_k order/tie-break. Stale candidates still
  // vanish for free (fresh ballot each round).
  auto half = [&](float dv, int g) {
    while (true) {
      u64 m = __ballot(dv < thresh);
      if (!m) break;
      int s = __ffsll((long long)m) - 1;
      float cv = rdlane_f(dv, s);         // wave-uniform candidate
      dv = (lane == s) ? INF : dv;        // kill inserted lane (the fix)
      int ci = g + s;                     // SALU
      float pvv = dpp_shr1_f(val, NINF_BITS);
      int piv = dpp_shr1_i(idx);
      bool p = cv < val;                  // strict < keeps stability
      bool p2 = cv < pvv;
      float nv = __builtin_amdgcn_fmed3f(val, pvv, cv);  // sorted-insert step
      idx = p ? (p2 ? piv : ci) : idx;
      val = nv;
      thresh = rdlane_f(val, 15);         // fresh 16th-best for next ballot
    }
  };

  auto dist = [&](f4 c0, f4 c1) -> f2 {
    // d2 = (qn+pn) + (qx*(-2px)+qy*(-2py)+qz*(-2pz)) == reference bit-exact
    f2 px = {c0[0], c0[1]}, py = {c0[2], c0[3]};
    f2 pz = {c1[0], c1[1]}, pw = {c1[2], c1[3]};
    f2 s1 = qx2 * px;
    f2 s2 = qy2 * py;
    f2 s3 = qz2 * pz;
    f2 t = (s1 + s2) + s3;
    return (qn2 + pw) + t;
  };

  if (PACKED) {
    const char* sbase = (const char*)(pp + (size_t)b * N);  // block-uniform
    u32 go = (u32)((widx << 11) + (lane << 5));  // this wave's global stage off
    u32 lo16 = (u32)(lane << 4);

    f4 s0, s1;  // reg staging (T14: load early, write late)
    auto stageLoad = [&](int t) {
      const char* p = sbase + ((size_t)t << 13) + go;
      s0 = *(const f4*)p;
      s1 = *(const f4*)(p + 16);
    };
    auto stageWrite = [&](int buf) {
      // chunk widx of super: plane0 at +0, plane1 at +1024 (stride-16 lanes,
      // conflict-free: 8 consecutive lanes cover all 32 banks)
      char* d = &smem[(buf << 13) + (widx << 11)];
      *(f4*)(d + lo16) = s0;
      *(f4*)(d + 1024 + lo16) = s1;
    };
    auto procChunk = [&](int buf, int c, int gbase) {
      const char* s = &smem[(buf << 13) + (c << 11)];
      f4 c0 = *(const f4*)(s + lo16);
      f4 c1 = *(const f4*)(s + 1024 + lo16);
      f2 d = dist(c0, c1);
      half(d.x, gbase);
      half(d.y, gbase + 64);
    };

    stageLoad(0);
    stageWrite(0);
    __syncthreads();
    stageLoad(1);
    {
      // ---- warmup: super 0 chunk 0, bitonic sort first 64 points ----
      const char* s = &smem[0];
      f4 c0 = *(const f4*)(s + lo16);
      f4 c1 = *(const f4*)(s + 1024 + lo16);
      f2 dA = dist(c0, c1);
      u64 key = ((u64)fkey(__float_as_uint(dA.x)) << 32) | (u32)lane;
#pragma unroll
      for (int k = 2; k <= 64; k <<= 1) {
#pragma unroll
        for (int j = k >> 1; j >= 1; j >>= 1) {
          u32 klo = (u32)key, khi = (u32)(key >> 32);
          u32 plo = (u32)__shfl_xor((int)klo, j);
          u32 phi = (u32)__shfl_xor((int)khi, j);
          u64 pkey = ((u64)phi << 32) | plo;
          bool keepMin = ((lane & j) == 0) == ((lane & k) == 0);
          bool lt = key < pkey;
          key = (lt == keepMin) ? key : pkey;
        }
      }
      {  // distribute sorted entries 0..15 to all four mirror rows
        int src = (lane & 15) << 2;
        u32 lo = (u32)__builtin_amdgcn_ds_bpermute(src, (int)(u32)key);
        u32 hi = (u32)__builtin_amdgcn_ds_bpermute(src, (int)(key >> 32));
        idx = (int)lo;
        val = __uint_as_float(hi ^ (((int)hi >= 0) ? 0xFFFFFFFFu : 0x80000000u));
        thresh = rdlane_f(val, 15);
      }
      half(dA.y, 64);
      procChunk(0, 1, 128);
      procChunk(0, 2, 256);
      procChunk(0, 3, 384);
    }
    stageWrite(1);
    __syncthreads();
    // ---- main loop over supers 1..14: stage t+1 while processing t ----
#pragma unroll 1
    for (int t = 1; t < 15; ++t) {
      stageLoad(t + 1);            // issue early; lands during processing
      int buf = t & 1;
      int gb = t << 9;
      procChunk(buf, 0, gb);
      procChunk(buf, 1, gb + 128);
      procChunk(buf, 2, gb + 256);
      procChunk(buf, 3, gb + 384);
      stageWrite((t + 1) & 1);     // vmcnt wait here is ~free (loads landed)
      __syncthreads();
    }
    {  // last super (15), no staging
      int gb = 15 << 9;
      procChunk(1, 0, gb);
      procChunk(1, 1, gb + 128);
      procChunk(1, 2, gb + 256);
      procChunk(1, 3, gb + 384);
    }
  } else {
#pragma unroll 1
    for (int g = 0; g < N; g += 64) {
      int n = g + lane;
      float x = pcb[n], y = pcb[N + n], z = pcb[2 * N + n];
      float pn = __fadd_rn(__fadd_rn(__fmul_rn(x, x), __fmul_rn(y, y)),
                           __fmul_rn(z, z));
      float s1 = __fmul_rn(qx, __fmul_rn(x, -2.0f));
      float s2 = __fmul_rn(qy, __fmul_rn(y, -2.0f));
      float s3 = __fmul_rn(qz, __fmul_rn(z, -2.0f));
      float t = __fadd_rn(__fadd_rn(s1, s2), s3);
      float d2 = __fadd_rn(__fadd_rn(qn, pn), t);
      half(d2, g);
    }
  }

  // ---- finisher (np-faithful): lane (l&15) owns entry (l&15) ----
  float Tv = temp[0];
  float sigma = fmaxf(__fmul_rn(Tv, Tv), 1e-4f);
  float sp = __fadd_rn(sigma, 1e-8f);
  int n = idx;
  float px = pcb[n], py = pcb[N + n], pz = pcb[2 * N + n];
  float dx = __fsub_rn(px, qx), dy = __fsub_rn(py, qy), dz = __fsub_rn(pz, qz);
  float d2w = __fadd_rn(__fadd_rn(__fmul_rn(dx, dx), __fmul_rn(dy, dy)),
                        __fmul_rn(dz, dz));
  float a = -__fdiv_rn(d2w, sp);   // -dist; softmax shift-invariant
  float m = rdlane_f(a, 0);        // entry 0 = nearest (sorted ascending)
  float e = expf(__fsub_rn(a, m));
  float Z = e;
#pragma unroll
  for (int d = 1; d < 16; d <<= 1) Z += __shfl_xor(Z, d, 16);
  float w = __fdiv_rn(e, Z);       // normalized weight
  float sx = __fmul_rn(px, w), sy = __fmul_rn(py, w), sz = __fmul_rn(pz, w);
#pragma unroll
  for (int d = 1; d < 16; d <<= 1) {
    sx += __shfl_xor(sx, d, 16);
    sy += __shfl_xor(sy, d, 16);
    sz += __shfl_xor(sz, d, 16);
  }
  if (lane < 3) {
    float r = (lane == 0) ? sx : ((lane == 1) ? sy : sz);
    out[(b * 3 + lane) * M + q] = r;
  }
}

extern "C" void kernel_launch(void* const* d_in, const int* in_sizes, int n_in,
                              void* d_out, int out_size, void* d_ws, size_t ws_size,
                              hipStream_t stream) {
  const int B = 8, N = 8192, M = 2048;
  const float* pc = (const float*)d_in[0];
  const float* qc = (const float*)d_in[1];
  const float* temp = (const float*)d_in[2];
  float* out = (float*)d_out;

  size_t packBytes = (size_t)B * N * 16;  // B*N/2 pairs * 32B
  bool packed = (ws_size >= packBytes) && (d_ws != nullptr);

  int nblocks = (B * M) / 4;  // 4 queries / 256-thread block (1 per wave)
  if (packed) {
    int R = B * (N >> 1);
    prep_pack2<<<dim3((R + 255) / 256), dim3(256), 0, stream>>>(
        pc, (float4*)d_ws, B, N);
    knn17<true><<<dim3(nblocks), dim3(256), 0, stream>>>(
        pc, qc, temp, (const float4*)d_ws, out, B, N, M);
  } else {
    knn17<false><<<dim3(nblocks), dim3(256), 0, stream>>>(
        pc, qc, temp, nullptr, out, B, N, M);
  }
}